// Round 1
// baseline (35.239 us; speedup 1.0000x reference)
//
#include <hip/hip_runtime.h>

#define B_DIM 32
#define O_DIM 1000
#define M_DIM 100
#define F_DIM 32
#define DS 6
#define DD 3

// Kernel 1: per (batch, o-segment) block computes partial softmax sums per m-column.
// partial layout: [B][S][M][8]  (0=denom, 1=sum p*pt, 2..7=sum p*raw_opes[o,d])
__global__ __launch_bounds__(256) void gat_partial(
    const float* __restrict__ raw_opes,   // [B,O,DS]
    const float* __restrict__ raw_mas,    // [B,M,DD]
    const float* __restrict__ proc_time,  // [B,O,M]
    const int*   __restrict__ adj,        // [Btot,O,M]
    const int*   __restrict__ bidx,       // [B]
    const float* __restrict__ Wsrc,       // [DS,F]
    const float* __restrict__ Wdst,       // [DD,F]
    const float* __restrict__ Wedge,      // [F]
    const float* __restrict__ attn_l,     // [F]
    const float* __restrict__ attn_r,     // [F]
    float* __restrict__ partial,
    int S, int chunk)
{
    const int b   = blockIdx.x / S;
    const int seg = blockIdx.x % S;
    const int t   = threadIdx.x;
    const int o0  = seg * chunk;
    const int o1  = min(O_DIM, o0 + chunk);
    const int n   = max(0, o1 - o0);

    __shared__ float el_s[O_DIM];
    __shared__ float ro_s[O_DIM * DS];
    __shared__ float part_s[2][M_DIM][8];

    // Folded weights (redundant per-thread; all-broadcast loads, cheap).
    float wl[DS] = {0, 0, 0, 0, 0, 0};
    float we = 0.f;
    for (int f = 0; f < F_DIM; ++f) {
        float al = attn_l[f];
        we = fmaf(Wedge[f], al, we);
        #pragma unroll
        for (int d = 0; d < DS; ++d) wl[d] = fmaf(Wsrc[d * F_DIM + f], al, wl[d]);
    }

    // Stage this segment's raw_opes into LDS (coalesced flat copy).
    const float* rop = raw_opes + ((size_t)b * O_DIM + o0) * DS;
    const int tot = n * DS;
    for (int i = t; i < tot; i += 256) ro_s[i] = rop[i];
    __syncthreads();

    // Local el for the segment.
    for (int i = t; i < n; i += 256) {
        float e = 0.f;
        #pragma unroll
        for (int d = 0; d < DS; ++d) e = fmaf(ro_s[i * DS + d], wl[d], e);
        el_s[i] = e;
    }
    __syncthreads();

    if (t < 2 * M_DIM) {
        const int m   = t % M_DIM;
        const int grp = t / M_DIM;

        // er[m] (redundant fold of W_dst@attn_r, then 3-dot).
        float wr[DD] = {0, 0, 0};
        for (int f = 0; f < F_DIM; ++f) {
            float ar = attn_r[f];
            #pragma unroll
            for (int d = 0; d < DD; ++d) wr[d] = fmaf(Wdst[d * F_DIM + f], ar, wr[d]);
        }
        float er = 0.f;
        #pragma unroll
        for (int d = 0; d < DD; ++d)
            er = fmaf(raw_mas[((size_t)b * M_DIM + m) * DD + d], wr[d], er);

        const float* ptp = proc_time + ((size_t)b * O_DIM + o0) * M_DIM + m;
        const int*   adp = adj + ((size_t)bidx[b] * O_DIM + o0) * M_DIM + m;

        float den = 0.f, spa = 0.f;
        float sd[DS] = {0, 0, 0, 0, 0, 0};
        for (int i = grp; i < n; i += 2) {
            float pt = ptp[i * M_DIM];
            int   av = adp[i * M_DIM];
            float s = el_s[i] + er + we * pt;
            s = fmaxf(s, 0.2f * s);                 // leaky relu (monotone)
            float p = (av == 1) ? __expf(s) : 0.f;  // zero-shift softmax (scores are O(10))
            den += p;
            spa = fmaf(p, pt, spa);
            #pragma unroll
            for (int d = 0; d < DS; ++d) sd[d] = fmaf(p, ro_s[i * DS + d], sd[d]);
        }
        part_s[grp][m][0] = den;
        part_s[grp][m][1] = spa;
        #pragma unroll
        for (int d = 0; d < DS; ++d) part_s[grp][m][2 + d] = sd[d];
    }
    __syncthreads();

    if (t < M_DIM) {
        float* dst = partial + (((size_t)b * S + seg) * M_DIM + t) * 8;
        #pragma unroll
        for (int k = 0; k < 8; ++k) dst[k] = part_s[0][t][k] + part_s[1][t][k];
    }
}

// Kernel 2: reduce segments, normalize, emit sigmoid output. Grid = B.
__global__ __launch_bounds__(256) void gat_final(
    const float* __restrict__ raw_mas,    // [B,M,DD]
    const float* __restrict__ Wsrc,       // [DS,F]
    const float* __restrict__ Wdst,       // [DD,F]
    const float* __restrict__ Wedge,      // [F]
    const float* __restrict__ attn_r,     // [F]
    const float* __restrict__ partial,
    float* __restrict__ out,              // [B,M,F]
    int S)
{
    const int b = blockIdx.x;
    const int t = threadIdx.x;

    __shared__ float smd[M_DIM][8];  // 0..5: sumd*inv, 6: spa*inv, 7: pkk*inv

    if (t < M_DIM) {
        const int m = t;
        float acc[8] = {0, 0, 0, 0, 0, 0, 0, 0};
        for (int seg = 0; seg < S; ++seg) {
            const float* p = partial + (((size_t)b * S + seg) * M_DIM + m) * 8;
            #pragma unroll
            for (int k = 0; k < 8; ++k) acc[k] += p[k];
        }
        float wr[DD] = {0, 0, 0};
        for (int f = 0; f < F_DIM; ++f) {
            float ar = attn_r[f];
            #pragma unroll
            for (int d = 0; d < DD; ++d) wr[d] = fmaf(Wdst[d * F_DIM + f], ar, wr[d]);
        }
        float er = 0.f;
        #pragma unroll
        for (int d = 0; d < DD; ++d)
            er = fmaf(raw_mas[((size_t)b * M_DIM + m) * DD + d], wr[d], er);
        float skk = 2.f * er;
        skk = fmaxf(skk, 0.2f * skk);
        float pkk = __expf(skk);
        float inv = 1.f / (acc[0] + pkk);
        #pragma unroll
        for (int d = 0; d < DS; ++d) smd[m][d] = acc[2 + d] * inv;
        smd[m][6] = acc[1] * inv;
        smd[m][7] = pkk * inv;
    }
    __syncthreads();

    for (int idx = t; idx < M_DIM * F_DIM; idx += 256) {
        const int m = idx >> 5;
        const int f = idx & 31;
        float v = smd[m][6] * Wedge[f];
        #pragma unroll
        for (int d = 0; d < DS; ++d) v = fmaf(smd[m][d], Wsrc[d * F_DIM + f], v);
        float fd = 0.f;
        #pragma unroll
        for (int d = 0; d < DD; ++d)
            fd = fmaf(raw_mas[((size_t)b * M_DIM + m) * DD + d], Wdst[d * F_DIM + f], fd);
        v = fmaf(fd, smd[m][7], v);
        out[((size_t)b * M_DIM + m) * F_DIM + f] = 1.f / (1.f + __expf(-v));
    }
}

extern "C" void kernel_launch(void* const* d_in, const int* in_sizes, int n_in,
                              void* d_out, int out_size, void* d_ws, size_t ws_size,
                              hipStream_t stream) {
    const float* raw_opes  = (const float*)d_in[0];
    const float* raw_mas   = (const float*)d_in[1];
    const float* proc_time = (const float*)d_in[2];
    const int*   adj       = (const int*)d_in[3];
    const int*   bidx      = (const int*)d_in[4];
    const float* Wsrc      = (const float*)d_in[5];
    const float* Wdst      = (const float*)d_in[6];
    const float* Wedge     = (const float*)d_in[7];
    const float* attn_l    = (const float*)d_in[8];
    const float* attn_r    = (const float*)d_in[9];
    float* out     = (float*)d_out;
    float* partial = (float*)d_ws;

    int S = 8;
    while (S > 1 && (size_t)B_DIM * S * M_DIM * 8 * sizeof(float) > ws_size) S >>= 1;
    const int chunk = (O_DIM + S - 1) / S;

    gat_partial<<<B_DIM * S, 256, 0, stream>>>(raw_opes, raw_mas, proc_time, adj, bidx,
                                               Wsrc, Wdst, Wedge, attn_l, attn_r,
                                               partial, S, chunk);
    gat_final<<<B_DIM, 256, 0, stream>>>(raw_mas, Wsrc, Wdst, Wedge, attn_r,
                                         partial, out, S);
}

// Round 2
// 28.666 us; speedup vs baseline: 1.2293x; 1.2293x over previous
//
#include <hip/hip_runtime.h>

#define B_DIM 32
#define O_DIM 1000
#define M_DIM 100
#define F_DIM 32
#define DS 6
#define DD 3
#define CH_MAX 128   // max o-chunk per segment (S >= 8 guaranteed by launcher)

// Kernel 1: per (batch, o-segment) block computes partial softmax sums per m-column.
// partial layout: [B][S][M][8]  (0=denom, 1=sum p*pt, 2..7=sum p*raw_opes[o,d])
__global__ __launch_bounds__(256) void gat_partial(
    const float* __restrict__ raw_opes,   // [B,O,DS]
    const float* __restrict__ raw_mas,    // [B,M,DD]
    const float* __restrict__ proc_time,  // [B,O,M]
    const int*   __restrict__ adj,        // [Btot,O,M]
    const int*   __restrict__ bidx,       // [B]
    const float* __restrict__ Wsrc,       // [DS,F]
    const float* __restrict__ Wdst,       // [DD,F]
    const float* __restrict__ Wedge,      // [F]
    const float* __restrict__ attn_l,     // [F]
    const float* __restrict__ attn_r,     // [F]
    float* __restrict__ partial,
    int S, int chunk)
{
    const int b   = blockIdx.x / S;
    const int seg = blockIdx.x % S;
    const int t   = threadIdx.x;
    const int o0  = seg * chunk;
    const int o1  = min(O_DIM, o0 + chunk);
    const int n   = max(0, o1 - o0);

    __shared__ float el_s[CH_MAX];
    __shared__ float ro_s[CH_MAX * DS];
    __shared__ float part_s[2][M_DIM][8];

    // Folded weights (uniform across block; scalarized loads).
    float wl[DS] = {0, 0, 0, 0, 0, 0};
    float we = 0.f;
    for (int f = 0; f < F_DIM; ++f) {
        float al = attn_l[f];
        we = fmaf(Wedge[f], al, we);
        #pragma unroll
        for (int d = 0; d < DS; ++d) wl[d] = fmaf(Wsrc[d * F_DIM + f], al, wl[d]);
    }

    // Stage this segment's raw_opes into LDS (coalesced flat copy).
    const float* rop = raw_opes + ((size_t)b * O_DIM + o0) * DS;
    const int tot = n * DS;
    for (int i = t; i < tot; i += 256) ro_s[i] = rop[i];
    __syncthreads();

    for (int i = t; i < n; i += 256) {
        float e = 0.f;
        #pragma unroll
        for (int d = 0; d < DS; ++d) e = fmaf(ro_s[i * DS + d], wl[d], e);
        el_s[i] = e;
    }
    __syncthreads();

    if (t < 2 * M_DIM) {
        const int m   = t % M_DIM;
        const int grp = t / M_DIM;

        float wr[DD] = {0, 0, 0};
        for (int f = 0; f < F_DIM; ++f) {
            float ar = attn_r[f];
            #pragma unroll
            for (int d = 0; d < DD; ++d) wr[d] = fmaf(Wdst[d * F_DIM + f], ar, wr[d]);
        }
        float er = 0.f;
        #pragma unroll
        for (int d = 0; d < DD; ++d)
            er = fmaf(raw_mas[((size_t)b * M_DIM + m) * DD + d], wr[d], er);

        const float* ptp = proc_time + ((size_t)b * O_DIM + o0) * M_DIM + m;
        const int*   adp = adj + ((size_t)bidx[b] * O_DIM + o0) * M_DIM + m;

        float den = 0.f, spa = 0.f;
        float sd[DS] = {0, 0, 0, 0, 0, 0};
        #pragma unroll 4
        for (int i = grp; i < n; i += 2) {
            float pt = ptp[i * M_DIM];
            int   av = adp[i * M_DIM];
            float s = el_s[i] + er + we * pt;
            s = fmaxf(s, 0.2f * s);                 // leaky relu (monotone)
            float p = (av == 1) ? __expf(s) : 0.f;  // zero-shift softmax (scores O(10))
            den += p;
            spa = fmaf(p, pt, spa);
            #pragma unroll
            for (int d = 0; d < DS; ++d) sd[d] = fmaf(p, ro_s[i * DS + d], sd[d]);
        }
        part_s[grp][m][0] = den;
        part_s[grp][m][1] = spa;
        #pragma unroll
        for (int d = 0; d < DS; ++d) part_s[grp][m][2 + d] = sd[d];
    }
    __syncthreads();

    if (t < M_DIM) {
        float4* dst = (float4*)(partial + (((size_t)b * S + seg) * M_DIM + t) * 8);
        const float* a = part_s[0][t];
        const float* c = part_s[1][t];
        dst[0] = make_float4(a[0] + c[0], a[1] + c[1], a[2] + c[2], a[3] + c[3]);
        dst[1] = make_float4(a[4] + c[4], a[5] + c[5], a[6] + c[6], a[7] + c[7]);
    }
}

// Kernel 2: reduce segments, normalize, emit sigmoid output. Grid = B.
__global__ __launch_bounds__(256) void gat_final(
    const float* __restrict__ raw_mas,    // [B,M,DD]
    const float* __restrict__ Wsrc,       // [DS,F]
    const float* __restrict__ Wdst,       // [DD,F]
    const float* __restrict__ Wedge,      // [F]
    const float* __restrict__ attn_r,     // [F]
    const float* __restrict__ partial,
    float* __restrict__ out,              // [B,M,F]
    int S)
{
    const int b = blockIdx.x;
    const int t = threadIdx.x;

    __shared__ float smd[M_DIM][8];  // 0..5: sumd*inv, 6: spa*inv, 7: pkk*inv

    if (t < M_DIM) {
        const int m = t;
        float4 a0 = make_float4(0, 0, 0, 0), a1 = make_float4(0, 0, 0, 0);
        const float4* p4 = (const float4*)(partial + (((size_t)b * S) * M_DIM + m) * 8);
        for (int seg = 0; seg < S; ++seg) {
            float4 x = p4[seg * M_DIM * 2];
            float4 y = p4[seg * M_DIM * 2 + 1];
            a0.x += x.x; a0.y += x.y; a0.z += x.z; a0.w += x.w;
            a1.x += y.x; a1.y += y.y; a1.z += y.z; a1.w += y.w;
        }
        float wr[DD] = {0, 0, 0};
        for (int f = 0; f < F_DIM; ++f) {
            float ar = attn_r[f];
            #pragma unroll
            for (int d = 0; d < DD; ++d) wr[d] = fmaf(Wdst[d * F_DIM + f], ar, wr[d]);
        }
        float er = 0.f;
        #pragma unroll
        for (int d = 0; d < DD; ++d)
            er = fmaf(raw_mas[((size_t)b * M_DIM + m) * DD + d], wr[d], er);
        float skk = 2.f * er;
        skk = fmaxf(skk, 0.2f * skk);
        float pkk = __expf(skk);
        float inv = 1.f / (a0.x + pkk);
        smd[m][0] = a0.z * inv;  // sum p*ro[,0]
        smd[m][1] = a0.w * inv;
        smd[m][2] = a1.x * inv;
        smd[m][3] = a1.y * inv;
        smd[m][4] = a1.z * inv;
        smd[m][5] = a1.w * inv;
        smd[m][6] = a0.y * inv;  // sum p*pt
        smd[m][7] = pkk * inv;
    }
    __syncthreads();

    for (int idx = t; idx < M_DIM * F_DIM; idx += 256) {
        const int m = idx >> 5;
        const int f = idx & 31;
        float v = smd[m][6] * Wedge[f];
        #pragma unroll
        for (int d = 0; d < DS; ++d) v = fmaf(smd[m][d], Wsrc[d * F_DIM + f], v);
        float fd = 0.f;
        #pragma unroll
        for (int d = 0; d < DD; ++d)
            fd = fmaf(raw_mas[((size_t)b * M_DIM + m) * DD + d], Wdst[d * F_DIM + f], fd);
        v = fmaf(fd, smd[m][7], v);
        out[((size_t)b * M_DIM + m) * F_DIM + f] = 1.f / (1.f + __expf(-v));
    }
}

extern "C" void kernel_launch(void* const* d_in, const int* in_sizes, int n_in,
                              void* d_out, int out_size, void* d_ws, size_t ws_size,
                              hipStream_t stream) {
    const float* raw_opes  = (const float*)d_in[0];
    const float* raw_mas   = (const float*)d_in[1];
    const float* proc_time = (const float*)d_in[2];
    const int*   adj       = (const int*)d_in[3];
    const int*   bidx      = (const int*)d_in[4];
    const float* Wsrc      = (const float*)d_in[5];
    const float* Wdst      = (const float*)d_in[6];
    const float* Wedge     = (const float*)d_in[7];
    const float* attn_l    = (const float*)d_in[8];
    const float* attn_r    = (const float*)d_in[9];
    float* out     = (float*)d_out;
    float* partial = (float*)d_ws;

    int S = 32;  // keep >= 8 so chunk <= CH_MAX
    while (S > 8 && (size_t)B_DIM * S * M_DIM * 8 * sizeof(float) > ws_size) S >>= 1;
    const int chunk = (O_DIM + S - 1) / S;

    gat_partial<<<B_DIM * S, 256, 0, stream>>>(raw_opes, raw_mas, proc_time, adj, bidx,
                                               Wsrc, Wdst, Wedge, attn_l, attn_r,
                                               partial, S, chunk);
    gat_final<<<B_DIM, 256, 0, stream>>>(raw_mas, Wsrc, Wdst, Wedge, attn_r,
                                         partial, out, S);
}

// Round 3
// 19.775 us; speedup vs baseline: 1.7820x; 1.4496x over previous
//
#include <hip/hip_runtime.h>

#define B_DIM 32
#define O_DIM 1000
#define M_DIM 100
#define F_DIM 32
#define DS 6
#define DD 3
#define SEG 25      // o-segments per batch
#define CHUNK 40    // O_DIM / SEG
#define OSUB 10     // o-subgroups per block
#define TRIPS 4     // CHUNK / OSUB

// Kernel 1: per (batch, o-segment) block computes partial softmax sums per m-column.
// partial layout: [B][SEG][M][8]  (0=denom, 1=sum p*pt, 2..7=sum p*raw_opes[o,d])
__global__ __launch_bounds__(256) void gat_partial(
    const float* __restrict__ raw_opes,   // [B,O,DS]
    const float* __restrict__ raw_mas,    // [B,M,DD]
    const float* __restrict__ proc_time,  // [B,O,M]
    const int*   __restrict__ adj,        // [Btot,O,M]
    const int*   __restrict__ bidx,       // [B]
    const float* __restrict__ Wsrc,       // [DS,F]
    const float* __restrict__ Wdst,       // [DD,F]
    const float* __restrict__ Wedge,      // [F]
    const float* __restrict__ attn_l,     // [F]
    const float* __restrict__ attn_r,     // [F]
    float* __restrict__ partial)
{
    const int b   = blockIdx.x / SEG;
    const int seg = blockIdx.x % SEG;
    const int t   = threadIdx.x;
    const int o0  = seg * CHUNK;

    __shared__ float ro_s[CHUNK * DS];            // staged raw_opes chunk
    __shared__ float part_s[OSUB][M_DIM][9];      // +1 pad to break bank conflicts

    // Folded weights (uniform -> scalar loads).
    float wl[DS] = {0, 0, 0, 0, 0, 0};
    float we = 0.f;
    for (int f = 0; f < F_DIM; ++f) {
        float al = attn_l[f];
        we = fmaf(Wedge[f], al, we);
        #pragma unroll
        for (int d = 0; d < DS; ++d) wl[d] = fmaf(Wsrc[d * F_DIM + f], al, wl[d]);
    }
    float wr[DD] = {0, 0, 0};
    for (int f = 0; f < F_DIM; ++f) {
        float ar = attn_r[f];
        #pragma unroll
        for (int d = 0; d < DD; ++d) wr[d] = fmaf(Wdst[d * F_DIM + f], ar, wr[d]);
    }

    // Stage this segment's raw_opes (240 floats).
    const float* rop = raw_opes + ((size_t)b * O_DIM + o0) * DS;
    if (t < CHUNK * DS) ro_s[t] = rop[t];
    __syncthreads();

    if (t < 25 * OSUB) {
        const int mg = t % 25;   // group of 4 consecutive m
        const int g  = t / 25;   // o-subgroup

        // er for this thread's 4 m's.
        const float* rm = raw_mas + ((size_t)b * M_DIM + mg * 4) * DD;
        float4 er;
        er.x = fmaf(rm[0], wr[0], fmaf(rm[1],  wr[1], rm[2]  * wr[2]));
        er.y = fmaf(rm[3], wr[0], fmaf(rm[4],  wr[1], rm[5]  * wr[2]));
        er.z = fmaf(rm[6], wr[0], fmaf(rm[7],  wr[1], rm[8]  * wr[2]));
        er.w = fmaf(rm[9], wr[0], fmaf(rm[10], wr[1], rm[11] * wr[2]));

        const float* ptp = proc_time + ((size_t)b * O_DIM + o0) * M_DIM + mg * 4;
        const int*   adp = adj + ((size_t)bidx[b] * O_DIM + o0) * M_DIM + mg * 4;

        float4 den = make_float4(0, 0, 0, 0), spa = make_float4(0, 0, 0, 0);
        float4 sd[DS];
        #pragma unroll
        for (int d = 0; d < DS; ++d) sd[d] = make_float4(0, 0, 0, 0);

        #pragma unroll
        for (int k = 0; k < TRIPS; ++k) {
            const int row = g + k * OSUB;
            float4 pt = *(const float4*)(ptp + row * M_DIM);
            int4   av = *(const int4*)(adp + row * M_DIM);
            float ro[DS];
            #pragma unroll
            for (int d = 0; d < DS; ++d) ro[d] = ro_s[row * DS + d];
            float elr = 0.f;
            #pragma unroll
            for (int d = 0; d < DS; ++d) elr = fmaf(ro[d], wl[d], elr);

            float s0 = elr + er.x + we * pt.x;
            float s1 = elr + er.y + we * pt.y;
            float s2 = elr + er.z + we * pt.z;
            float s3 = elr + er.w + we * pt.w;
            s0 = fmaxf(s0, 0.2f * s0); s1 = fmaxf(s1, 0.2f * s1);
            s2 = fmaxf(s2, 0.2f * s2); s3 = fmaxf(s3, 0.2f * s3);
            float p0 = (av.x == 1) ? __expf(s0) : 0.f;
            float p1 = (av.y == 1) ? __expf(s1) : 0.f;
            float p2 = (av.z == 1) ? __expf(s2) : 0.f;
            float p3 = (av.w == 1) ? __expf(s3) : 0.f;
            den.x += p0; den.y += p1; den.z += p2; den.w += p3;
            spa.x = fmaf(p0, pt.x, spa.x); spa.y = fmaf(p1, pt.y, spa.y);
            spa.z = fmaf(p2, pt.z, spa.z); spa.w = fmaf(p3, pt.w, spa.w);
            #pragma unroll
            for (int d = 0; d < DS; ++d) {
                sd[d].x = fmaf(p0, ro[d], sd[d].x);
                sd[d].y = fmaf(p1, ro[d], sd[d].y);
                sd[d].z = fmaf(p2, ro[d], sd[d].z);
                sd[d].w = fmaf(p3, ro[d], sd[d].w);
            }
        }

        #pragma unroll
        for (int j = 0; j < 4; ++j) {
            const int m = mg * 4 + j;
            float* ps = part_s[g][m];
            ps[0] = j == 0 ? den.x : j == 1 ? den.y : j == 2 ? den.z : den.w;
            ps[1] = j == 0 ? spa.x : j == 1 ? spa.y : j == 2 ? spa.z : spa.w;
            #pragma unroll
            for (int d = 0; d < DS; ++d)
                ps[2 + d] = j == 0 ? sd[d].x : j == 1 ? sd[d].y : j == 2 ? sd[d].z : sd[d].w;
        }
    }
    __syncthreads();

    // Reduce over OSUB groups and write [m][8] partials.
    if (t < 2 * M_DIM) {
        const int m = t % M_DIM, half = t / M_DIM;
        float a[4] = {0, 0, 0, 0};
        #pragma unroll
        for (int g = 0; g < OSUB; ++g) {
            #pragma unroll
            for (int k = 0; k < 4; ++k) a[k] += part_s[g][m][half * 4 + k];
        }
        *(float4*)(partial + (((size_t)b * SEG + seg) * M_DIM + m) * 8 + half * 4) =
            make_float4(a[0], a[1], a[2], a[3]);
    }
}

// Kernel 2: reduce segments, normalize, emit sigmoid output. Grid = B.
__global__ __launch_bounds__(256) void gat_final(
    const float* __restrict__ raw_mas,    // [B,M,DD]
    const float* __restrict__ Wsrc,       // [DS,F]
    const float* __restrict__ Wdst,       // [DD,F]
    const float* __restrict__ Wedge,      // [F]
    const float* __restrict__ attn_r,     // [F]
    const float* __restrict__ partial,
    float* __restrict__ out)              // [B,M,F]
{
    const int b = blockIdx.x;
    const int t = threadIdx.x;

    __shared__ float smd[M_DIM][8];

    if (t < 2 * M_DIM) {
        const int m = t % M_DIM, half = t / M_DIM;
        const float4* p4 = (const float4*)(partial + (((size_t)b * SEG) * M_DIM + m) * 8 + half * 4);
        float4 acc = make_float4(0, 0, 0, 0);
        #pragma unroll
        for (int s = 0; s < SEG; ++s) {
            float4 x = p4[s * M_DIM * 2];
            acc.x += x.x; acc.y += x.y; acc.z += x.z; acc.w += x.w;
        }
        smd[m][half * 4 + 0] = acc.x;
        smd[m][half * 4 + 1] = acc.y;
        smd[m][half * 4 + 2] = acc.z;
        smd[m][half * 4 + 3] = acc.w;
    }
    __syncthreads();

    if (t < M_DIM) {
        const int m = t;
        float wr[DD] = {0, 0, 0};
        for (int f = 0; f < F_DIM; ++f) {
            float ar = attn_r[f];
            #pragma unroll
            for (int d = 0; d < DD; ++d) wr[d] = fmaf(Wdst[d * F_DIM + f], ar, wr[d]);
        }
        const float* rm = raw_mas + ((size_t)b * M_DIM + m) * DD;
        float er = fmaf(rm[0], wr[0], fmaf(rm[1], wr[1], rm[2] * wr[2]));
        float skk = 2.f * er;
        skk = fmaxf(skk, 0.2f * skk);
        float pkk = __expf(skk);
        float inv = 1.f / (smd[m][0] + pkk);
        float spa = smd[m][1];
        float s0 = smd[m][2], s1 = smd[m][3], s2 = smd[m][4],
              s3 = smd[m][5], s4 = smd[m][6], s5 = smd[m][7];
        smd[m][0] = s0 * inv; smd[m][1] = s1 * inv; smd[m][2] = s2 * inv;
        smd[m][3] = s3 * inv; smd[m][4] = s4 * inv; smd[m][5] = s5 * inv;
        smd[m][6] = spa * inv;
        smd[m][7] = pkk * inv;
    }
    __syncthreads();

    for (int idx = t; idx < M_DIM * F_DIM; idx += 256) {
        const int m = idx >> 5;
        const int f = idx & 31;
        float v = smd[m][6] * Wedge[f];
        #pragma unroll
        for (int d = 0; d < DS; ++d) v = fmaf(smd[m][d], Wsrc[d * F_DIM + f], v);
        const float* rm = raw_mas + ((size_t)b * M_DIM + m) * DD;
        float fd = 0.f;
        #pragma unroll
        for (int d = 0; d < DD; ++d) fd = fmaf(rm[d], Wdst[d * F_DIM + f], fd);
        v = fmaf(fd, smd[m][7], v);
        out[((size_t)b * M_DIM + m) * F_DIM + f] = 1.f / (1.f + __expf(-v));
    }
}

extern "C" void kernel_launch(void* const* d_in, const int* in_sizes, int n_in,
                              void* d_out, int out_size, void* d_ws, size_t ws_size,
                              hipStream_t stream) {
    const float* raw_opes  = (const float*)d_in[0];
    const float* raw_mas   = (const float*)d_in[1];
    const float* proc_time = (const float*)d_in[2];
    const int*   adj       = (const int*)d_in[3];
    const int*   bidx      = (const int*)d_in[4];
    const float* Wsrc      = (const float*)d_in[5];
    const float* Wdst      = (const float*)d_in[6];
    const float* Wedge     = (const float*)d_in[7];
    const float* attn_l    = (const float*)d_in[8];
    const float* attn_r    = (const float*)d_in[9];
    float* out     = (float*)d_out;
    float* partial = (float*)d_ws;   // needs 32*25*100*8*4 = 2.56 MB

    gat_partial<<<B_DIM * SEG, 256, 0, stream>>>(raw_opes, raw_mas, proc_time, adj, bidx,
                                                 Wsrc, Wdst, Wedge, attn_l, attn_r, partial);
    gat_final<<<B_DIM, 256, 0, stream>>>(raw_mas, Wsrc, Wdst, Wedge, attn_r, partial, out);
}